// Round 14
// baseline (579.020 us; speedup 1.0000x reference)
//
#include <hip/hip_runtime.h>
#include <math.h>

#define Bq 8
#define Nn 1024
#define Cc 256
#define Hh 8
#define HDd 32
#define Ll 225
#define SCALE 0.17677669529663687f
#define LOG2E 1.44269504088896f

typedef __fp16 f16;
typedef __fp16 half8 __attribute__((ext_vector_type(8)));
typedef __fp16 half2t __attribute__((ext_vector_type(2)));
typedef float float4v __attribute__((ext_vector_type(4)));

__device__ __forceinline__ int iclamp7(int x) {
    return x < -7 ? -7 : (x > 7 ? 7 : x);
}
__device__ __forceinline__ float fexp2(float x) {
    float r;
    asm("v_exp_f32 %0, %1" : "=v"(r) : "v"(x));
    return r;
}

// ---------------- K1: QKV projection (f32 in, f16 out; Q x LOG2E; V into vcat) ----------------
__global__ __launch_bounds__(256) void qkv_gemm(const float* __restrict__ x,
                                                const float* __restrict__ w,
                                                f16* __restrict__ q16,
                                                f16* __restrict__ k16,
                                                f16* __restrict__ vcat) {
    __shared__ float As[16][65];
    __shared__ float Bs[16][65];
    const int tix = threadIdx.x;
    const int tx = tix & 15, ty = tix >> 4;
    const int row0 = blockIdx.y * 64;
    const int col0 = blockIdx.x * 64;
    float acc[4][4] = {};
    for (int k0 = 0; k0 < Cc; k0 += 16) {
#pragma unroll
        for (int r = 0; r < 4; ++r) {
            int idx = tix + r * 256;
            int m = idx >> 4, kk = idx & 15;
            As[kk][m] = x[(size_t)(row0 + m) * Cc + k0 + kk];
            Bs[kk][m] = w[(size_t)(col0 + m) * Cc + k0 + kk];
        }
        __syncthreads();
#pragma unroll
        for (int kk = 0; kk < 16; ++kk) {
            float a[4], b[4];
#pragma unroll
            for (int i = 0; i < 4; ++i) a[i] = As[kk][ty * 4 + i];
#pragma unroll
            for (int j = 0; j < 4; ++j) b[j] = Bs[kk][tx * 4 + j];
#pragma unroll
            for (int i = 0; i < 4; ++i)
#pragma unroll
                for (int j = 0; j < 4; ++j) acc[i][j] = fmaf(a[i], b[j], acc[i][j]);
        }
        __syncthreads();
    }
#pragma unroll
    for (int i = 0; i < 4; ++i) {
        int row = row0 + ty * 4 + i;
        int b = row >> 10, n = row & 1023;
#pragma unroll
        for (int j = 0; j < 4; ++j) {
            int oc = col0 + tx * 4 + j;
            int which = oc >> 8;
            int h = (oc >> 5) & 7;
            int d = oc & 31;
            int bh = b * Hh + h;
            if (which == 0)
                q16[((size_t)bh * Nn + n) * HDd + d] = (f16)(acc[i][j] * LOG2E);
            else if (which == 1)
                k16[((size_t)bh * Nn + n) * HDd + d] = (f16)acc[i][j];
            else
                vcat[((size_t)bh * 1280 + n) * HDd + d] = (f16)acc[i][j];
        }
    }
}

// ---------------- K1b: prep tables + vcat tail ----------------
__global__ __launch_bounds__(256) void prep_kernel(const float* __restrict__ rpek,
                                                   const float* __restrict__ rpeq,
                                                   const float* __restrict__ rpev,
                                                   f16* __restrict__ rk16,
                                                   f16* __restrict__ rq16,
                                                   f16* __restrict__ vcat) {
    const int bh = blockIdx.x;
    const int h = bh & 7;
    // vcat rows 1024..1279 for this bh
    for (int idx = threadIdx.x; idx < 256 * 32; idx += 256) {
        int l = idx >> 5, d = idx & 31;
        float val = (l < Ll) ? rpev[((size_t)h * Ll + l) * HDd + d] : 0.f;
        vcat[((size_t)bh * 1280 + 1024 + l) * HDd + d] = (f16)val;
    }
    if (bh < 8) {
        for (int idx = threadIdx.x; idx < 240 * 32; idx += 256) {
            int l = idx >> 5, d = idx & 31;
            float vk = (l < Ll) ? rpek[((size_t)bh * Ll + l) * HDd + d] : 0.f;
            float vq = (l < Ll) ? rpeq[((size_t)bh * Ll + l) * HDd + d] * (SCALE * LOG2E) : 0.f;
            rk16[((size_t)bh * 240 + l) * HDd + d] = (f16)vk;
            rq16[((size_t)bh * 240 + l) * HDd + d] = (f16)vq;
        }
    }
}

// ---------------- K2: bias-table GEMMs: TK = Q.rk^T, TQ = K.rq^T ----------------
__global__ __launch_bounds__(256) void tbl_gemm(const f16* __restrict__ q16,
                                                const f16* __restrict__ k16,
                                                const f16* __restrict__ rk16,
                                                const f16* __restrict__ rq16,
                                                f16* __restrict__ TK,
                                                f16* __restrict__ TQ,
                                                int bh0) {
    const int tid = threadIdx.x;
    const int lane = tid & 63;
    const int w = tid >> 6;
    const int li = lane & 15;
    const int g = lane >> 4;
    const int i0 = blockIdx.x * 64;
    const int y = blockIdx.y;
    const int bh = bh0 + y;
    const int h = bh & 7;
    const int which = blockIdx.z;
    const f16* A = which ? k16 : q16;
    const f16* B = which ? rq16 : rk16;
    f16* O = which ? TQ : TK;

    half8 aF = *(const half8*)(A + ((size_t)bh * Nn + i0 + w * 16 + li) * HDd + 8 * g);
#pragma unroll 1
    for (int lt = 0; lt < 15; ++lt) {
        half8 bF = *(const half8*)(B + ((size_t)h * 240 + lt * 16 + li) * HDd + 8 * g);
        float4v c = {0.f, 0.f, 0.f, 0.f};
        c = __builtin_amdgcn_mfma_f32_16x16x32_f16(aF, bF, c, 0, 0, 0);
#pragma unroll
        for (int r = 0; r < 4; ++r)
            O[((size_t)y * Nn + i0 + w * 16 + 4 * g + r) * 240 + lt * 16 + li] = (f16)c[r];
    }
}

// ---------------- K3: softmax + P + A (S^T layout, lane-owns-row, no atomics) ----------------
__global__ __launch_bounds__(128) void sfmx_kernel(const f16* __restrict__ q16,
                                                   const f16* __restrict__ k16,
                                                   const f16* __restrict__ TK,
                                                   const f16* __restrict__ TQ,
                                                   f16* __restrict__ PpT,
                                                   float* __restrict__ Z,
                                                   int bh0) {
    __shared__ f16 sTKb[32 * 244];
    __shared__ float sA[32 * 226];

    const int tid = threadIdx.x;
    const int lane = tid & 63;
    const int w = tid >> 6;       // 0..1
    const int li = lane & 15;
    const int g = lane >> 4;
    const int x = blockIdx.x;     // band = ri
    const int y = blockIdx.y;
    const int bh = bh0 + y;
    const int i0 = x * 32;
    const int ib = i0 + w * 16;
    const int ci = w * 16 + li;   // i & 31 for this lane's row
    const size_t qkbase = (size_t)bh * Nn * HDd;

    // stage TK band + zero sA
    for (int idx = tid; idx < 32 * 30; idx += 128) {
        int row = idx / 30, seg = idx % 30;
        *(half8*)(sTKb + row * 244 + seg * 8) =
            *(const half8*)(TK + ((size_t)y * Nn + i0 + row) * 240 + seg * 8);
    }
    for (int idx = tid; idx < 32 * 226; idx += 128) sA[idx] = 0.f;

    half8 bQ = *(const half8*)(q16 + qkbase + (size_t)(ib + li) * HDd + 8 * g);

    // ---- pass 1: raw QK^T row max (lane-local rows) ----
    float mq = -1.0e30f;
#pragma unroll 1
    for (int c = 0; c < 32; ++c) {
        int jt = c * 32;
        half8 aK0 = *(const half8*)(k16 + qkbase + (size_t)(jt + li) * HDd + 8 * g);
        half8 aK1 = *(const half8*)(k16 + qkbase + (size_t)(jt + 16 + li) * HDd + 8 * g);
        float4v cz = {0.f, 0.f, 0.f, 0.f};
        float4v s0 = __builtin_amdgcn_mfma_f32_16x16x32_f16(aK0, bQ, cz, 0, 0, 0);
        float4v s1 = __builtin_amdgcn_mfma_f32_16x16x32_f16(aK1, bQ, cz, 0, 0, 0);
        mq = fmaxf(mq, fmaxf(fmaxf(s0[0], s0[1]), fmaxf(s0[2], s0[3])));
        mq = fmaxf(mq, fmaxf(fmaxf(s1[0], s1[1]), fmaxf(s1[2], s1[3])));
    }
    mq = fmaxf(mq, __shfl_xor(mq, 16));
    mq = fmaxf(mq, __shfl_xor(mq, 32));
    const float mrow = mq + 6.0f;   // bias bound headroom; p <= ~2^-2.5, max term >= 2^-9.5

    __syncthreads();   // sTKb + sA ready

    // ---- pass 2: recompute S, add biases, exp, write P, accumulate A ----
    float z = 0.f;
    float* arow = sA + ci * 226;
    const f16* tkrow = sTKb + ci * 244;
#pragma unroll 1
    for (int c = 0; c < 32; ++c) {
        const int jt = c * 32;
        const int dr = iclamp7(x - c);
        const int drb = dr * 15 + 112;
        half8 aK0 = *(const half8*)(k16 + qkbase + (size_t)(jt + li) * HDd + 8 * g);
        half8 aK1 = *(const half8*)(k16 + qkbase + (size_t)(jt + 16 + li) * HDd + 8 * g);
        float4v cz = {0.f, 0.f, 0.f, 0.f};
        float4v s0 = __builtin_amdgcn_mfma_f32_16x16x32_f16(aK0, bQ, cz, 0, 0, 0);
        float4v s1 = __builtin_amdgcn_mfma_f32_16x16x32_f16(aK1, bQ, cz, 0, 0, 0);
#pragma unroll
        for (int jf = 0; jf < 2; ++jf) {
            const int cip = ci - jf * 16;
            float s7 = 0.f, sm7 = 0.f;
#pragma unroll
            for (int r = 0; r < 4; ++r) {
                const int t = 4 * g + r;
                const int dcm = cip - t;
                const int dc = iclamp7(dcm);
                const int b = drb + dc;
                float sv = (jf ? s1[r] : s0[r]);
                sv += (float)tkrow[b];
                const int j = jt + jf * 16 + t;
                sv += (float)TQ[((size_t)y * Nn + j) * 240 + (224 - b)];
                float p = fexp2(sv - mrow);
                z += p;
                PpT[((size_t)y * 1280 + j) * Nn + ib + li] = (f16)p;
                if (dcm >= 7) s7 += p;
                else if (dcm <= -7) sm7 += p;
                else arow[b] += p;     // unique (lane,col) -> no race
            }
            s7 += __shfl_xor(s7, 16);  s7 += __shfl_xor(s7, 32);
            sm7 += __shfl_xor(sm7, 16); sm7 += __shfl_xor(sm7, 32);
            if (g == 0) {
                if (s7 != 0.f)  arow[drb + 7] += s7;
                if (sm7 != 0.f) arow[drb - 7] += sm7;
            }
        }
    }
    z += __shfl_xor(z, 16);
    z += __shfl_xor(z, 32);
    if (g == 0) Z[(size_t)bh * Nn + ib + li] = z;

    __syncthreads();   // sA complete
    // write A rows into PpT rows 1024..1263 (cols = i)
    for (int idx = tid; idx < 240 * 32; idx += 128) {
        int l = idx >> 5, ic = idx & 31;
        float val = (l < Ll) ? sA[ic * 226 + l] : 0.f;
        PpT[((size_t)y * 1280 + 1024 + l) * Nn + i0 + ic] = (f16)val;
    }
}

// ---------------- K4: O^T = vcat^T . PpT  (PV + A.rpe_v fused), /z ----------------
#define PV_SMEM (32 * 1288 * 2)
__global__ __launch_bounds__(256, 1) void pv_gemm(const f16* __restrict__ vcat,
                                                  const f16* __restrict__ PpT,
                                                  const float* __restrict__ Z,
                                                  float* __restrict__ ctx,
                                                  int bh0) {
    extern __shared__ f16 sVT[];   // [32][1288]
    const int tid = threadIdx.x;
    const int lane = tid & 63;
    const int w = tid >> 6;
    const int li = lane & 15;
    const int g = lane >> 4;
    const int y = blockIdx.y;
    const int bh = bh0 + y;
    const int i0 = blockIdx.x * 128;
    const int iw = i0 + w * 32;

    // stage vcat^T
    for (int idx = tid; idx < 1280 * 4; idx += 256) {
        int kk = idx >> 2, d0 = (idx & 3) * 8;
        half8 v8 = *(const half8*)(vcat + ((size_t)bh * 1280 + kk) * HDd + d0);
#pragma unroll
        for (int e = 0; e < 8; ++e) sVT[(d0 + e) * 1288 + kk] = v8[e];
    }
    __syncthreads();

    const f16* pb = PpT + (size_t)y * 1280 * Nn;
    float4v o00 = {0,0,0,0}, o01 = {0,0,0,0}, o10 = {0,0,0,0}, o11 = {0,0,0,0};
#pragma unroll 1
    for (int k0 = 0; k0 < 1280; k0 += 32) {
        half8 A0 = *(const half8*)(sVT + li * 1288 + k0 + 8 * g);
        half8 A1 = *(const half8*)(sVT + (16 + li) * 1288 + k0 + 8 * g);
        union { half8 v8; f16 e[8]; } B0, B1;
#pragma unroll
        for (int e = 0; e < 8; ++e) {
            B0.e[e] = pb[(size_t)(k0 + 8 * g + e) * Nn + iw + li];
            B1.e[e] = pb[(size_t)(k0 + 8 * g + e) * Nn + iw + 16 + li];
        }
        o00 = __builtin_amdgcn_mfma_f32_16x16x32_f16(A0, B0.v8, o00, 0, 0, 0);
        o01 = __builtin_amdgcn_mfma_f32_16x16x32_f16(A0, B1.v8, o01, 0, 0, 0);
        o10 = __builtin_amdgcn_mfma_f32_16x16x32_f16(A1, B0.v8, o10, 0, 0, 0);
        o11 = __builtin_amdgcn_mfma_f32_16x16x32_f16(A1, B1.v8, o11, 0, 0, 0);
    }
    const float rzA = 1.0f / Z[(size_t)bh * Nn + iw + li];
    const float rzB = 1.0f / Z[(size_t)bh * Nn + iw + 16 + li];
    float* cb = ctx + (size_t)bh * Nn * HDd;
#pragma unroll
    for (int r = 0; r < 4; ++r) {
        cb[(size_t)(iw + li) * HDd + 4 * g + r]           = o00[r] * rzA;
        cb[(size_t)(iw + li) * HDd + 16 + 4 * g + r]      = o10[r] * rzA;
        cb[(size_t)(iw + 16 + li) * HDd + 4 * g + r]      = o01[r] * rzB;
        cb[(size_t)(iw + 16 + li) * HDd + 16 + 4 * g + r] = o11[r] * rzB;
    }
}

// ---------------- K5a: partial mean over tokens (ctx [bh][n][d]) ----------------
__global__ __launch_bounds__(256) void reduce_partial(const float* __restrict__ ctx,
                                                      const float* __restrict__ x,
                                                      float* __restrict__ pcm,
                                                      float* __restrict__ pxm) {
    int b = blockIdx.x >> 4, s = blockIdx.x & 15;
    int c = threadIdx.x;
    int h = c >> 5, d = c & 31;
    float sc = 0.f, sx = 0.f;
    for (int n = s * 64; n < s * 64 + 64; ++n) {
        sc += ctx[((size_t)(b * 8 + h) * Nn + n) * HDd + d];
        sx += x[((size_t)b * Nn + n) * Cc + c];
    }
    pcm[(size_t)blockIdx.x * 256 + c] = sc;
    pxm[(size_t)blockIdx.x * 256 + c] = sx;
}

// ---------------- K5b: final proj(mean) + residual-mean + fc ----------------
__global__ __launch_bounds__(256) void final_kernel(const float* __restrict__ pcm,
                                                    const float* __restrict__ pxm,
                                                    const float* __restrict__ pw,
                                                    const float* __restrict__ pb,
                                                    const float* __restrict__ fcw,
                                                    const float* __restrict__ fcb,
                                                    float* __restrict__ out) {
    __shared__ float cm[256], xm[256], mrow[256];
    int b = blockIdx.x;
    int c = threadIdx.x;
    float sc = 0.f, sx = 0.f;
    for (int s2 = 0; s2 < 16; ++s2) {
        sc += pcm[((size_t)b * 16 + s2) * 256 + c];
        sx += pxm[((size_t)b * 16 + s2) * 256 + c];
    }
    cm[c] = sc * (1.f / 1024.f);
    xm[c] = sx * (1.f / 1024.f);
    __syncthreads();
    float acc = pb[c] + xm[c];
    for (int c2 = 0; c2 < 256; ++c2) acc = fmaf(cm[c2], pw[(size_t)c * 256 + c2], acc);
    mrow[c] = acc;
    __syncthreads();
    if (c < 15) {
        float a2 = fcb[c];
        for (int c2 = 0; c2 < 256; ++c2) a2 = fmaf(mrow[c2], fcw[(size_t)c * 256 + c2], a2);
        out[b * 15 + c] = a2;
    }
}

extern "C" void kernel_launch(void* const* d_in, const int* in_sizes, int n_in,
                              void* d_out, int out_size, void* d_ws, size_t ws_size,
                              hipStream_t stream) {
    const float* x     = (const float*)d_in[0];
    const float* qkv_w = (const float*)d_in[1];
    const float* pw    = (const float*)d_in[2];
    const float* pb    = (const float*)d_in[3];
    const float* fcw   = (const float*)d_in[4];
    const float* fcb   = (const float*)d_in[5];
    const float* rpek  = (const float*)d_in[6];
    const float* rpeq  = (const float*)d_in[7];
    const float* rpev  = (const float*)d_in[8];
    float* out = (float*)d_out;

    // fixed-size buffers
    char* p = (char*)d_ws;
    const size_t q16B  = (size_t)64 * 1024 * 32 * 2;     // 4 MB
    const size_t vcatB = (size_t)64 * 1280 * 32 * 2;     // 5.24 MB
    const size_t rkB   = (size_t)8 * 240 * 32 * 2;
    const size_t ZB    = (size_t)64 * 1024 * 4;
    const size_t ctxB  = (size_t)64 * 1024 * 32 * 4;
    const size_t pcmB  = (size_t)128 * 256 * 4;
    f16* q16  = (f16*)p;           p += q16B;
    f16* k16  = (f16*)p;           p += q16B;
    f16* vcat = (f16*)p;           p += vcatB;
    f16* rk16 = (f16*)p;           p += rkB;
    f16* rq16 = (f16*)p;           p += rkB;
    float* Z  = (float*)p;         p += ZB;
    float* ctx = (float*)p;        p += ctxB;
    float* pcm = (float*)p;        p += pcmB;
    float* pxm = (float*)p;        p += pcmB;
    const size_t fixedB = (size_t)(p - (char*)d_ws);

    const size_t TKh = (size_t)1024 * 240 * 2;       // per head
    const size_t PpTh = (size_t)1280 * 1024 * 2;     // per head
    const size_t perHead = 2 * TKh + PpTh;           // ~3.6 MB
    int NC = 64;
    while (NC > 1 && fixedB + (size_t)NC * perHead > ws_size) NC >>= 1;
    f16* TK  = (f16*)p;
    f16* TQ  = TK + (size_t)NC * 1024 * 240;
    f16* PpT = TQ + (size_t)NC * 1024 * 240;

    hipFuncSetAttribute((const void*)pv_gemm,
                        hipFuncAttributeMaxDynamicSharedMemorySize, PV_SMEM);

    qkv_gemm<<<dim3(12, 128), 256, 0, stream>>>(x, qkv_w, q16, k16, vcat);
    prep_kernel<<<64, 256, 0, stream>>>(rpek, rpeq, rpev, rk16, rq16, vcat);

    for (int bh0 = 0; bh0 < 64; bh0 += NC) {
        tbl_gemm<<<dim3(16, NC, 2), 256, 0, stream>>>(q16, k16, rk16, rq16, TK, TQ, bh0);
        sfmx_kernel<<<dim3(32, NC), 128, 0, stream>>>(q16, k16, TK, TQ, PpT, Z, bh0);
        pv_gemm<<<dim3(8, NC), 256, PV_SMEM, stream>>>(vcat, PpT, Z, ctx, bh0);
    }

    reduce_partial<<<128, 256, 0, stream>>>(ctx, x, pcm, pxm);
    final_kernel<<<8, 256, 0, stream>>>(pcm, pxm, pw, pb, fcw, fcb, out);
}

// Round 15
// 279.768 us; speedup vs baseline: 2.0696x; 2.0696x over previous
//
#include <hip/hip_runtime.h>
#include <math.h>

#define Bq 8
#define Nn 1024
#define Cc 256
#define Hh 8
#define HDd 32
#define Ll 225
#define SCALE 0.17677669529663687f
#define LOG2E 1.44269504088896f

typedef __fp16 f16;
typedef __fp16 half8 __attribute__((ext_vector_type(8)));
typedef __fp16 half2t __attribute__((ext_vector_type(2)));
typedef float float4v __attribute__((ext_vector_type(4)));

__device__ __forceinline__ int iclamp7(int x) {
    return x < -7 ? -7 : (x > 7 ? 7 : x);
}
__device__ __forceinline__ float fexp2(float x) {
    float r;
    asm("v_exp_f32 %0, %1" : "=v"(r) : "v"(x));
    return r;
}

// ---------------- K1: QKV projection (f32 in, f16 out; Q x LOG2E) ----------------
__global__ __launch_bounds__(256) void qkv_gemm(const float* __restrict__ x,
                                                const float* __restrict__ w,
                                                f16* __restrict__ q16,
                                                f16* __restrict__ k16,
                                                f16* __restrict__ v16) {
    __shared__ float As[16][65];
    __shared__ float Bs[16][65];
    const int tix = threadIdx.x;
    const int tx = tix & 15, ty = tix >> 4;
    const int row0 = blockIdx.y * 64;
    const int col0 = blockIdx.x * 64;
    float acc[4][4] = {};
    for (int k0 = 0; k0 < Cc; k0 += 16) {
#pragma unroll
        for (int r = 0; r < 4; ++r) {
            int idx = tix + r * 256;
            int m = idx >> 4, kk = idx & 15;
            As[kk][m] = x[(size_t)(row0 + m) * Cc + k0 + kk];
            Bs[kk][m] = w[(size_t)(col0 + m) * Cc + k0 + kk];
        }
        __syncthreads();
#pragma unroll
        for (int kk = 0; kk < 16; ++kk) {
            float a[4], b[4];
#pragma unroll
            for (int i = 0; i < 4; ++i) a[i] = As[kk][ty * 4 + i];
#pragma unroll
            for (int j = 0; j < 4; ++j) b[j] = Bs[kk][tx * 4 + j];
#pragma unroll
            for (int i = 0; i < 4; ++i)
#pragma unroll
                for (int j = 0; j < 4; ++j) acc[i][j] = fmaf(a[i], b[j], acc[i][j]);
        }
        __syncthreads();
    }
#pragma unroll
    for (int i = 0; i < 4; ++i) {
        int row = row0 + ty * 4 + i;
        int b = row >> 10, n = row & 1023;
#pragma unroll
        for (int j = 0; j < 4; ++j) {
            int oc = col0 + tx * 4 + j;
            int which = oc >> 8;
            int h = (oc >> 5) & 7;
            int d = oc & 31;
            int bh = b * Hh + h;
            if (which == 0)
                q16[((size_t)bh * Nn + n) * HDd + d] = (f16)(acc[i][j] * LOG2E);
            else if (which == 1)
                k16[((size_t)bh * Nn + n) * HDd + d] = (f16)acc[i][j];
            else
                v16[((size_t)bh * Nn + n) * HDd + d] = (f16)acc[i][j];
        }
    }
}

// ---------------- K1b: prep — bias tables f16, packed V-frags, packed rpev-frags ----------------
// pi(kslot): e<4 -> t=4g+e ; e>=4 -> t=16+4g+(e-4)
__global__ __launch_bounds__(256) void prep_kernel(const float* __restrict__ rpek,
                                                   const float* __restrict__ rpeq,
                                                   const float* __restrict__ rpev,
                                                   const f16* __restrict__ v16,
                                                   f16* __restrict__ rk16,
                                                   f16* __restrict__ rq16,
                                                   f16* __restrict__ vPack,
                                                   f16* __restrict__ rvPack) {
    const int bh = blockIdx.x;
    const int h = bh & 7;
    // vPack[bh][c 32][half 2][lane 64] half8
    for (int slot = threadIdx.x; slot < 32 * 2 * 64; slot += 256) {
        int c = slot >> 7, half = (slot >> 6) & 1, lane = slot & 63;
        int li = lane & 15, g = lane >> 4;
        half8 val;
#pragma unroll
        for (int e = 0; e < 8; ++e) {
            int t = (e < 4) ? (4 * g + e) : (16 + 4 * g + e - 4);
            val[e] = v16[((size_t)bh * Nn + c * 32 + t) * HDd + half * 16 + li];
        }
        *(half8*)(vPack + ((size_t)(bh * 32 + c) * 2 + half) * 64 * 8 + lane * 8) = val;
    }
    if (bh < 8) {
        for (int idx = threadIdx.x; idx < 240 * 32; idx += 256) {
            int l = idx >> 5, d = idx & 31;
            float vk = (l < Ll) ? rpek[((size_t)h * Ll + l) * HDd + d] : 0.f;
            float vq = (l < Ll) ? rpeq[((size_t)h * Ll + l) * HDd + d] * (SCALE * LOG2E) : 0.f;
            rk16[((size_t)h * 240 + l) * HDd + d] = (f16)vk;
            rq16[((size_t)h * 240 + l) * HDd + d] = (f16)vq;
        }
        // rvPack[h][kt 8][half 2][lane 64] half8 ; identity k-order, l = kt*32+8g+e
        for (int slot = threadIdx.x; slot < 8 * 2 * 64; slot += 256) {
            int kt = slot >> 7, half = (slot >> 6) & 1, lane = slot & 63;
            int li = lane & 15, g = lane >> 4;
            half8 val;
#pragma unroll
            for (int e = 0; e < 8; ++e) {
                int l = kt * 32 + 8 * g + e;
                val[e] = (l < Ll) ? (f16)rpev[((size_t)h * Ll + l) * HDd + half * 16 + li]
                                  : (f16)0.f;
            }
            *(half8*)(rvPack + ((size_t)(h * 8 + kt) * 2 + half) * 64 * 8 + lane * 8) = val;
        }
    }
}

// ---------------- K2: bias-table GEMMs: TK = Q.rk^T, TQ = K.rq^T ----------------
__global__ __launch_bounds__(256) void tbl_gemm(const f16* __restrict__ q16,
                                                const f16* __restrict__ k16,
                                                const f16* __restrict__ rk16,
                                                const f16* __restrict__ rq16,
                                                f16* __restrict__ TK,
                                                f16* __restrict__ TQ,
                                                int bh0) {
    const int tid = threadIdx.x;
    const int lane = tid & 63;
    const int w = tid >> 6;
    const int li = lane & 15;
    const int g = lane >> 4;
    const int i0 = blockIdx.x * 64;
    const int y = blockIdx.y;
    const int bh = bh0 + y;
    const int h = bh & 7;
    const int which = blockIdx.z;
    const f16* A = which ? k16 : q16;
    const f16* B = which ? rq16 : rk16;
    f16* O = which ? TQ : TK;

    half8 aF = *(const half8*)(A + ((size_t)bh * Nn + i0 + w * 16 + li) * HDd + 8 * g);
#pragma unroll 1
    for (int lt = 0; lt < 15; ++lt) {
        half8 bF = *(const half8*)(B + ((size_t)h * 240 + lt * 16 + li) * HDd + 8 * g);
        float4v c = {0.f, 0.f, 0.f, 0.f};
        c = __builtin_amdgcn_mfma_f32_16x16x32_f16(aF, bF, c, 0, 0, 0);
#pragma unroll
        for (int r = 0; r < 4; ++r)
            O[((size_t)y * Nn + i0 + w * 16 + 4 * g + r) * 240 + lt * 16 + li] = (f16)c[r];
    }
}

// ---------------- K3: softmax + Ppack + A + Z (S^T layout, f16 sA, high occupancy) ----------------
__global__ __launch_bounds__(128) void sfmx_kernel(const f16* __restrict__ q16,
                                                   const f16* __restrict__ k16,
                                                   const f16* __restrict__ TK,
                                                   const f16* __restrict__ TQ,
                                                   f16* __restrict__ Ppack,
                                                   f16* __restrict__ AT,
                                                   float* __restrict__ Z,
                                                   int bh0) {
    __shared__ f16 sTKb[32 * 244];   // 15.6 KB
    __shared__ f16 sA[32 * 232];     // 14.8 KB  (cols 226..231 stay 0)

    const int tid = threadIdx.x;
    const int lane = tid & 63;
    const int w = tid >> 6;        // 0..1
    const int li = lane & 15;
    const int g = lane >> 4;
    const int x = blockIdx.x;      // band (ri)
    const int y = blockIdx.y;
    const int bh = bh0 + y;
    const int i0 = x * 32;
    const int ci = w * 16 + li;
    const int i = i0 + ci;
    const size_t qkbase = (size_t)bh * Nn * HDd;

    // stage TK band
    for (int idx = tid; idx < 32 * 30; idx += 128) {
        int row = idx / 30, seg = idx % 30;
        *(half8*)(sTKb + row * 244 + seg * 8) =
            *(const half8*)(TK + ((size_t)y * Nn + i0 + row) * 240 + seg * 8);
    }
    // zero sA
    {
        half8 z8 = {};
        for (int idx = tid; idx < 32 * 232 / 8; idx += 128)
            *(half8*)(sA + idx * 8) = z8;
    }

    half8 bQ = *(const half8*)(q16 + qkbase + (size_t)i * HDd + 8 * g);

    // lane-constant tables for the 8 t-slots (t = 4g+u | 16+4g+(u-4))
    int tarr[8], dccu[8], dcCl[8];
    float mask7[8], maskm7[8];
    bool mid[8];
#pragma unroll
    for (int u = 0; u < 8; ++u) {
        int t = (u < 4) ? (4 * g + u) : (16 + 4 * g + u - 4);
        tarr[u] = t;
        dccu[u] = ci - t;
        dcCl[u] = iclamp7(ci - t);
        mask7[u] = (dccu[u] >= 7) ? 1.f : 0.f;
        maskm7[u] = (dccu[u] <= -7) ? 1.f : 0.f;
        mid[u] = (dccu[u] > -7) && (dccu[u] < 7);
    }

    // ---- pass 1: raw row max ----
    float mq = -1.0e30f;
#pragma unroll 1
    for (int c = 0; c < 32; ++c) {
        half8 aK0 = *(const half8*)(k16 + qkbase + (size_t)(c * 32 + li) * HDd + 8 * g);
        half8 aK1 = *(const half8*)(k16 + qkbase + (size_t)(c * 32 + 16 + li) * HDd + 8 * g);
        float4v cz = {0.f, 0.f, 0.f, 0.f};
        float4v s0 = __builtin_amdgcn_mfma_f32_16x16x32_f16(aK0, bQ, cz, 0, 0, 0);
        float4v s1 = __builtin_amdgcn_mfma_f32_16x16x32_f16(aK1, bQ, cz, 0, 0, 0);
        mq = fmaxf(mq, fmaxf(fmaxf(s0[0], s0[1]), fmaxf(s0[2], s0[3])));
        mq = fmaxf(mq, fmaxf(fmaxf(s1[0], s1[1]), fmaxf(s1[2], s1[3])));
    }
    mq = fmaxf(mq, __shfl_xor(mq, 16));
    mq = fmaxf(mq, __shfl_xor(mq, 32));
    const float mrow = mq + 6.0f;

    __syncthreads();   // sTKb + sA ready

    // ---- pass 2 ----
    float zacc = 0.f;
    const f16* tkrow = sTKb + ci * 244;
    f16* arow = sA + ci * 232;
#pragma unroll 1
    for (int c = 0; c < 32; ++c) {
        const int dr = iclamp7(x - c);
        const int drb = dr * 15 + 112;
        const int colb = 224 - drb;
        half8 aK0 = *(const half8*)(k16 + qkbase + (size_t)(c * 32 + li) * HDd + 8 * g);
        half8 aK1 = *(const half8*)(k16 + qkbase + (size_t)(c * 32 + 16 + li) * HDd + 8 * g);
        float4v cz = {0.f, 0.f, 0.f, 0.f};
        float4v s0 = __builtin_amdgcn_mfma_f32_16x16x32_f16(aK0, bQ, cz, 0, 0, 0);
        float4v s1 = __builtin_amdgcn_mfma_f32_16x16x32_f16(aK1, bQ, cz, 0, 0, 0);
        const f16* tqbase = TQ + ((size_t)y * Nn + c * 32) * 240 + colb;
        float tkv[8], tqv[8];
#pragma unroll
        for (int u = 0; u < 8; ++u) {
            tkv[u] = (float)tkrow[drb + dcCl[u]];
            tqv[u] = (float)tqbase[tarr[u] * 240 - dcCl[u]];
        }
        float p[8];
#pragma unroll
        for (int u = 0; u < 8; ++u) {
            float sv = ((u < 4) ? s0[u] : s1[u - 4]) + tkv[u] + tqv[u];
            p[u] = fexp2(sv - mrow);
            zacc += p[u];
        }
        // Ppack store (fragment layout; one 16B store)
        union { half8 v8; half2t hh[4]; } up;
        up.hh[0] = __builtin_amdgcn_cvt_pkrtz(p[0], p[1]);
        up.hh[1] = __builtin_amdgcn_cvt_pkrtz(p[2], p[3]);
        up.hh[2] = __builtin_amdgcn_cvt_pkrtz(p[4], p[5]);
        up.hh[3] = __builtin_amdgcn_cvt_pkrtz(p[6], p[7]);
        *(half8*)(Ppack + ((size_t)(y * 32 + c) * 64 + (x * 2 + w)) * 64 * 8 + lane * 8) = up.v8;
        // A scatter: middle lane-unique RMW; edges reduced
        float s7 = 0.f, sm7 = 0.f;
#pragma unroll
        for (int u = 0; u < 8; ++u) {
            s7 = fmaf(mask7[u], p[u], s7);
            sm7 = fmaf(maskm7[u], p[u], sm7);
            if (mid[u]) arow[drb + dccu[u]] += (f16)p[u];
        }
        s7 += __shfl_xor(s7, 16);  s7 += __shfl_xor(s7, 32);
        sm7 += __shfl_xor(sm7, 16); sm7 += __shfl_xor(sm7, 32);
        if (g == 0) {
            arow[drb + 7] += (f16)s7;
            arow[drb - 7] += (f16)sm7;
        }
    }
    zacc += __shfl_xor(zacc, 16);
    zacc += __shfl_xor(zacc, 32);
    if (g == 0) Z[(size_t)bh * Nn + i] = zacc;

    __syncthreads();   // sA complete
    // AT copy: [i][256] rows, zeros beyond 231
    {
        half8 z8 = {};
        for (int idx = tid; idx < 32 * 32; idx += 128) {
            int row = idx >> 5, seg = idx & 31;
            half8 v = (seg < 29) ? *(const half8*)(sA + row * 232 + seg * 8) : z8;
            *(half8*)(AT + ((size_t)y * Nn + i0 + row) * 256 + seg * 8) = v;
        }
    }
}

// ---------------- K4: pv — dense MFMA over packed fragments, zero LDS ----------------
__global__ __launch_bounds__(256) void pv_gemm(const f16* __restrict__ Ppack,
                                               const f16* __restrict__ vPack,
                                               const f16* __restrict__ AT,
                                               const f16* __restrict__ rvPack,
                                               const float* __restrict__ Z,
                                               float* __restrict__ ctx,
                                               int bh0) {
    const int tid = threadIdx.x;
    const int lane = tid & 63;
    const int w = tid >> 6;
    const int li = lane & 15;
    const int g = lane >> 4;
    const int y = blockIdx.y;
    const int bh = bh0 + y;
    const int h = bh & 7;
    const int ig = blockIdx.x * 4 + w;   // 0..63

    float4v a0 = {0,0,0,0}, a1 = {0,0,0,0};
#pragma unroll 1
    for (int c = 0; c < 32; ++c) {
        half8 P = *(const half8*)(Ppack + ((size_t)(y * 32 + c) * 64 + ig) * 64 * 8 + lane * 8);
        half8 V0 = *(const half8*)(vPack + ((size_t)(bh * 32 + c) * 2 + 0) * 64 * 8 + lane * 8);
        half8 V1 = *(const half8*)(vPack + ((size_t)(bh * 32 + c) * 2 + 1) * 64 * 8 + lane * 8);
        a0 = __builtin_amdgcn_mfma_f32_16x16x32_f16(P, V0, a0, 0, 0, 0);
        a1 = __builtin_amdgcn_mfma_f32_16x16x32_f16(P, V1, a1, 0, 0, 0);
    }
#pragma unroll 1
    for (int kt = 0; kt < 8; ++kt) {
        half8 A = *(const half8*)(AT + ((size_t)y * Nn + ig * 16 + li) * 256 + kt * 32 + 8 * g);
        half8 R0 = *(const half8*)(rvPack + ((size_t)(h * 8 + kt) * 2 + 0) * 64 * 8 + lane * 8);
        half8 R1 = *(const half8*)(rvPack + ((size_t)(h * 8 + kt) * 2 + 1) * 64 * 8 + lane * 8);
        a0 = __builtin_amdgcn_mfma_f32_16x16x32_f16(A, R0, a0, 0, 0, 0);
        a1 = __builtin_amdgcn_mfma_f32_16x16x32_f16(A, R1, a1, 0, 0, 0);
    }
#pragma unroll
    for (int r = 0; r < 4; ++r) {
        int i = ig * 16 + 4 * g + r;
        float rz = 1.0f / Z[(size_t)bh * Nn + i];
        ctx[((size_t)bh * Nn + i) * HDd + li]      = a0[r] * rz;
        ctx[((size_t)bh * Nn + i) * HDd + 16 + li] = a1[r] * rz;
    }
}

// ---------------- K5a: partial mean over tokens (ctx [bh][n][d]) ----------------
__global__ __launch_bounds__(256) void reduce_partial(const float* __restrict__ ctx,
                                                      const float* __restrict__ x,
                                                      float* __restrict__ pcm,
                                                      float* __restrict__ pxm) {
    int b = blockIdx.x >> 4, s = blockIdx.x & 15;
    int c = threadIdx.x;
    int h = c >> 5, d = c & 31;
    float sc = 0.f, sx = 0.f;
    for (int n = s * 64; n < s * 64 + 64; ++n) {
        sc += ctx[((size_t)(b * 8 + h) * Nn + n) * HDd + d];
        sx += x[((size_t)b * Nn + n) * Cc + c];
    }
    pcm[(size_t)blockIdx.x * 256 + c] = sc;
    pxm[(size_t)blockIdx.x * 256 + c] = sx;
}

// ---------------- K5b: final proj(mean) + residual-mean + fc ----------------
__global__ __launch_bounds__(256) void final_kernel(const float* __restrict__ pcm,
                                                    const float* __restrict__ pxm,
                                                    const float* __restrict__ pw,
                                                    const float* __restrict__ pb,
                                                    const float* __restrict__ fcw,
                                                    const float* __restrict__ fcb,
                                                    float* __restrict__ out) {
    __shared__ float cm[256], xm[256], mrow[256];
    int b = blockIdx.x;
    int c = threadIdx.x;
    float sc = 0.f, sx = 0.f;
    for (int s2 = 0; s2 < 16; ++s2) {
        sc += pcm[((size_t)b * 16 + s2) * 256 + c];
        sx += pxm[((size_t)b * 16 + s2) * 256 + c];
    }
    cm[c] = sc * (1.f / 1024.f);
    xm[c] = sx * (1.f / 1024.f);
    __syncthreads();
    float acc = pb[c] + xm[c];
    for (int c2 = 0; c2 < 256; ++c2) acc = fmaf(cm[c2], pw[(size_t)c * 256 + c2], acc);
    mrow[c] = acc;
    __syncthreads();
    if (c < 15) {
        float a2 = fcb[c];
        for (int c2 = 0; c2 < 256; ++c2) a2 = fmaf(mrow[c2], fcw[(size_t)c * 256 + c2], a2);
        out[b * 15 + c] = a2;
    }
}

extern "C" void kernel_launch(void* const* d_in, const int* in_sizes, int n_in,
                              void* d_out, int out_size, void* d_ws, size_t ws_size,
                              hipStream_t stream) {
    const float* x     = (const float*)d_in[0];
    const float* qkv_w = (const float*)d_in[1];
    const float* pw    = (const float*)d_in[2];
    const float* pb    = (const float*)d_in[3];
    const float* fcw   = (const float*)d_in[4];
    const float* fcb   = (const float*)d_in[5];
    const float* rpek  = (const float*)d_in[6];
    const float* rpeq  = (const float*)d_in[7];
    const float* rpev  = (const float*)d_in[8];
    float* out = (float*)d_out;

    char* p = (char*)d_ws;
    const size_t qB     = (size_t)64 * Nn * HDd * 2;          // 4 MB each
    const size_t vPackB = (size_t)64 * 32 * 2 * 64 * 8 * 2;   // 4 MB
    const size_t rkB    = (size_t)8 * 240 * HDd * 2;
    const size_t rvPB   = (size_t)8 * 8 * 2 * 64 * 8 * 2;     // 128 KB
    const size_t ZB     = (size_t)64 * Nn * 4;
    const size_t ctxB   = (size_t)64 * Nn * HDd * 4;
    const size_t pcmB   = (size_t)128 * 256 * 4;
    f16* q16   = (f16*)p;  p += qB;
    f16* k16   = (f16*)p;  p += qB;
    f16* v16   = (f16*)p;  p += qB;
    f16* vPack = (f16*)p;  p += vPackB;
    f16* rk16  = (f16*)p;  p += rkB;
    f16* rq16  = (f16*)p;  p += rkB;
    f16* rvPack= (f16*)p;  p += rvPB;
    float* Z   = (float*)p; p += ZB;
    float* ctx = (float*)p; p += ctxB;
    float* pcm = (float*)p; p += pcmB;
    float* pxm = (float*)p; p += pcmB;
    const size_t fixedB = (size_t)(p - (char*)d_ws);

    const size_t TKh = (size_t)Nn * 240 * 2;
    const size_t PpH = (size_t)32 * 64 * 64 * 8 * 2;          // 2 MB
    const size_t ATh = (size_t)Nn * 256 * 2;                  // 0.5 MB
    const size_t perHead = 2 * TKh + PpH + ATh;
    int NC = 64;
    while (NC > 1 && fixedB + (size_t)NC * perHead > ws_size) NC >>= 1;
    f16* TK    = (f16*)p;
    f16* TQ    = TK + (size_t)NC * Nn * 240;
    f16* Ppack = TQ + (size_t)NC * Nn * 240;
    f16* AT    = Ppack + (size_t)NC * 32 * 64 * 64 * 8;

    qkv_gemm<<<dim3(12, 128), 256, 0, stream>>>(x, qkv_w, q16, k16, v16);
    prep_kernel<<<64, 256, 0, stream>>>(rpek, rpeq, rpev, v16, rk16, rq16, vPack, rvPack);

    for (int bh0 = 0; bh0 < 64; bh0 += NC) {
        tbl_gemm<<<dim3(16, NC, 2), 256, 0, stream>>>(q16, k16, rk16, rq16, TK, TQ, bh0);
        sfmx_kernel<<<dim3(32, NC), 128, 0, stream>>>(q16, k16, TK, TQ, Ppack, AT, Z, bh0);
        pv_gemm<<<dim3(16, NC), 256, 0, stream>>>(Ppack, vPack, AT, rvPack, Z, ctx, bh0);
    }

    reduce_partial<<<128, 256, 0, stream>>>(ctx, x, pcm, pxm);
    final_kernel<<<8, 256, 0, stream>>>(pcm, pxm, pw, pb, fcw, fcb, out);
}